// Round 1
// baseline (341.200 us; speedup 1.0000x reference)
//
#include <hip/hip_runtime.h>

// GCN pull-mode, round 13. Theory: the F=64 aggregates are bound by random
// 128-B line requests missing L2 (4MB/XCD) and round-tripping to LLC at
// ~27G lines/s. Fix: feature-sliced aggregation — split 64-wide features
// into 4 slice-major arrays of 32 B/node (3.2 MB each, L2-resident per
// XCD via slice = blockIdx%4 against the round-robin bid->XCD mapping).
// Gathers become 32-B L2 hits. csr/aux streams use nontemporal hints so
// they don't evict the slice. The MFMA chains split out into small
// streaming GEMM kernels (mega fusion impossible across slice blocks).
//   bbuild: xs sliced -> hQ
//   agg64s: A1 = dis*agg(hQ) sliced -> hP
//   gemm1:  Z2 = dis*(relu(A1@W1+b1)@W2) sliced -> hQ
//   agg64s: A2 = dis*agg(hQ) sliced -> hP
//   gemm2:  Z3 = dis*(relu(A2+b2)@W3) row-major 32 -> hQ
//   agg32_gemm4, final: unchanged (controls; Z4 already L2-fits naturally)
// 9 dispatches total.

#define TPB 256
#define NBUCK 782    // ceil(100000/128)
#define BCAP 3072    // fixed slot size; mean 2047, +22 sigma headroom
#define CHUNK 8192   // edges per block in scatter

typedef __attribute__((ext_vector_type(8))) _Float16 half8;
typedef __attribute__((ext_vector_type(4))) _Float16 half4;
typedef __attribute__((ext_vector_type(4))) float f32x4;

// --- Scatter packed edges into fixed bucket slots ---
__global__ void bscatter_kernel(const int* __restrict__ src, const int* __restrict__ dst,
                                int* __restrict__ bcur, int* __restrict__ bsort, int E) {
    __shared__ int h[NBUCK];
    __shared__ int cur[NBUCK];
    int tid = threadIdx.x;
    for (int i = tid; i < NBUCK; i += blockDim.x) h[i] = 0;
    __syncthreads();
    int base = blockIdx.x * CHUNK;
    int lim = min(base + CHUNK, E);
    for (int e = base + tid; e < lim; e += blockDim.x)
        atomicAdd(&h[dst[e] >> 7], 1);
    __syncthreads();
    for (int i = tid; i < NBUCK; i += blockDim.x)
        cur[i] = h[i] ? (atomicAdd(&bcur[i], h[i]) + i * BCAP) : 0;
    __syncthreads();
    for (int e = base + tid; e < lim; e += blockDim.x) {
        int d = dst[e];
        int pos = atomicAdd(&cur[d >> 7], 1);
        bsort[pos] = ((d & 127) << 17) | src[e];  // src < 2^17
    }
}

// --- Per-bucket local sort -> csr slot; rowstart/rowdeg/dis; X prescale ---
// xs now written in SLICED layout: hQ[slice][node][16 halfs], slice = feat>>4.
__global__ __launch_bounds__(256) void bbuild_kernel(
        const int* __restrict__ bcur, const int* __restrict__ bsort,
        int* __restrict__ csr, int* __restrict__ rowstart, int* __restrict__ rowdeg,
        float* __restrict__ dis,
        const float4* __restrict__ x4, _Float16* __restrict__ xs,
        int N) {
    __shared__ int ebuf[BCAP];
    __shared__ int obuf[BCAP];
    __shared__ int cnt[128];
    __shared__ int off[129];
    __shared__ float sdis[128];
    int b = blockIdx.x;
    int tid = threadIdx.x;
    int ebase = b * BCAP;
    int n = min(bcur[b], BCAP);
    if (tid < 128) cnt[tid] = 0;
    __syncthreads();
    for (int i = tid; i < n; i += 256) {
        int p = bsort[ebase + i];
        ebuf[i] = p;
        atomicAdd(&cnt[p >> 17], 1);
    }
    __syncthreads();
    if (tid < 64) {
        int lane = tid;
        int v0 = cnt[lane];
#pragma unroll
        for (int d = 1; d < 64; d <<= 1) { int u = __shfl_up(v0, d, 64); if (lane >= d) v0 += u; }
        off[lane + 1] = v0;
        int tot0 = __shfl(v0, 63, 64);
        int v1 = cnt[64 + lane];
#pragma unroll
        for (int d = 1; d < 64; d <<= 1) { int u = __shfl_up(v1, d, 64); if (lane >= d) v1 += u; }
        off[64 + lane + 1] = tot0 + v1;
        if (lane == 0) off[0] = 0;
    }
    __syncthreads();
    int node0 = b << 7;
    if (tid < 128 && node0 + tid < N) {
        int deg = off[tid + 1] - off[tid];
        rowstart[node0 + tid] = ebase + off[tid];
        rowdeg[node0 + tid] = deg;
        float d = rsqrtf((float)deg + 1.0f);
        dis[node0 + tid] = d;
        sdis[tid] = d;
    }
    if (tid < 128) cnt[tid] = off[tid];  // reuse as cursor
    __syncthreads();
    for (int i = tid; i < n; i += 256) {
        int p = ebuf[i];
        int pos = atomicAdd(&cnt[p >> 17], 1);
        obuf[pos] = p & 0x1FFFF;
    }
    __syncthreads();
    for (int i = tid; i < n; i += 256)
        csr[ebase + i] = obuf[i];
    // fused prescale: xs[slice][node][0..15] = half(x[node][f] * dis[node])
    for (int i = tid; i < 128 * 16; i += 256) {
        int r = i >> 4, c = i & 15;          // c: float4 index, feats 4c..4c+3
        int node = node0 + r;
        if (node >= N) break;
        float d = sdis[r];
        float4 v = x4[(size_t)node * 16 + c];
        half4 h;
        h[0] = (_Float16)(v.x * d); h[1] = (_Float16)(v.y * d);
        h[2] = (_Float16)(v.z * d); h[3] = (_Float16)(v.w * d);
        int sl = c >> 2;
        int off16 = (c & 3) * 4;
        *(half4*)(xs + ((size_t)sl * N + node) * 16 + off16) = h;
    }
}

// Transpose + fp16-convert weights (Wt[m*K+k] = half(W[k*M+m])); zero bcur.
// Sections: W1t 96x64 @0, W2t 64x96 @6144, W3t 32x64 @12288, W4t 16x32 @14336.
__global__ void wprep_kernel(const float* __restrict__ W1, const float* __restrict__ W2,
                             const float* __restrict__ W3, const float* __restrict__ W4,
                             _Float16* __restrict__ wt, int* __restrict__ bcur) {
    int t = blockIdx.x * blockDim.x + threadIdx.x;
    if (t < 788) bcur[t] = 0;
    if (t < 6144) {
        int m = t / 64, k = t % 64;
        wt[t] = (_Float16)W1[k * 96 + m];
    } else if (t < 12288) {
        int i = t - 6144; int m = i / 96, k = i % 96;
        wt[t] = (_Float16)W2[k * 64 + m];
    } else if (t < 14336) {
        int i = t - 12288; int m = i / 64, k = i % 64;
        wt[t] = (_Float16)W3[k * 32 + m];
    } else if (t < 14848) {
        int i = t - 14336; int m = i / 32, k = i % 32;
        wt[t] = (_Float16)W4[k * 16 + m];
    }
}

// Sliced F=64 aggregation: block = (slice = bid&3, chunk = bid>>2).
// Each XCD (bid%8 round-robin) only touches slice bid%4 -> 3.2MB, L2-resident.
// outs[slice][node][16] = dis[node] * (sum_{s in nbr(node)} hs[slice][s][16] + self).
__global__ __launch_bounds__(256) void agg64s_kernel(
        const _Float16* __restrict__ hs, const int* __restrict__ rowstart,
        const int* __restrict__ rowdeg, const int* __restrict__ csr,
        const float* __restrict__ dis, _Float16* __restrict__ outs, int N) {
    int bid = blockIdx.x;
    int sl = bid & 3;
    int chunk = bid >> 2;
    const _Float16* hb = hs + (size_t)sl * N * 16;
    int tid = threadIdx.x;
    int wid = tid >> 6;
    int lane = tid & 63;
    int srow = lane >> 3;    // 8 rows per wave
    int l2 = lane & 7;
    int g = l2 >> 1;         // 4 edge groups per row
    int q = l2 & 1;          // 2 lanes x half8 = 32-B slice row
    int row = chunk * 32 + wid * 8 + srow;
    if (row >= N) return;    // no barriers below
    int start = rowstart[row];
    int end = start + rowdeg[row];
    float a0[8] = {}, a1[8] = {};
    if (g == 0) {  // self loop
        half8 v = *(const half8*)(hb + (size_t)row * 16 + 8 * q);
#pragma unroll
        for (int j = 0; j < 8; ++j) a0[j] = (float)v[j];
    }
    int e = start + g;
    for (; e + 4 < end; e += 8) {
        int s0 = __builtin_nontemporal_load(csr + e);
        int s1 = __builtin_nontemporal_load(csr + e + 4);
        half8 v0 = *(const half8*)(hb + (size_t)s0 * 16 + 8 * q);
        half8 v1 = *(const half8*)(hb + (size_t)s1 * 16 + 8 * q);
#pragma unroll
        for (int j = 0; j < 8; ++j) { a0[j] += (float)v0[j]; a1[j] += (float)v1[j]; }
    }
    for (; e < end; e += 4) {
        int s = __builtin_nontemporal_load(csr + e);
        half8 v = *(const half8*)(hb + (size_t)s * 16 + 8 * q);
#pragma unroll
        for (int j = 0; j < 8; ++j) a0[j] += (float)v[j];
    }
#pragma unroll
    for (int j = 0; j < 8; ++j) a0[j] += a1[j];
#pragma unroll
    for (int m = 2; m < 8; m <<= 1) {
#pragma unroll
        for (int j = 0; j < 8; ++j) a0[j] += __shfl_xor(a0[j], m, 64);
    }
    if (g == 0) {
        float d = dis[row];
        half8 h;
#pragma unroll
        for (int j = 0; j < 8; ++j) h[j] = (_Float16)(a0[j] * d);
        __builtin_nontemporal_store(h, (half8*)(outs + ((size_t)sl * N + row) * 16 + 8 * q));
    }
}

// gemm1: Z2 = dis * (relu(A1@W1 + b1) @ W2), A1 sliced in, Z2 sliced out.
// 4 waves x 16 rows = 64 rows/block; per-wave sT tile for re-fragmentation.
__global__ __launch_bounds__(256) void gemm1_kernel(
        const _Float16* __restrict__ A1, const _Float16* __restrict__ W1t,
        const float* __restrict__ b1, const _Float16* __restrict__ W2t,
        const float* __restrict__ dis, _Float16* __restrict__ Z2s, int N) {
    __shared__ _Float16 sT[4][16 * 96];
    int tid = threadIdx.x;
    int wid = tid >> 6;
    int lane = tid & 63;
    int quad = lane >> 4, m16 = lane & 15;
    int tile = blockIdx.x * 4 + wid;
    int ntile = N >> 4;  // N divisible by 16
    bool act = tile < ntile;
    int rbase = tile * 16;
    if (act) {
        half8 a[2];
#pragma unroll
        for (int kt = 0; kt < 2; ++kt) {
            int sl = kt * 2 + (quad >> 1);   // k0 = kt*32 + quad*8; slice = k0>>4
            a[kt] = *(const half8*)(A1 + ((size_t)sl * N + rbase + m16) * 16 + (quad & 1) * 8);
        }
#pragma unroll
        for (int ct = 0; ct < 6; ++ct) {
            f32x4 c = {0.f, 0.f, 0.f, 0.f};
#pragma unroll
            for (int kt = 0; kt < 2; ++kt) {
                half8 b = *(const half8*)(W1t + (size_t)(ct * 16 + m16) * 64 + kt * 32 + quad * 8);
                c = __builtin_amdgcn_mfma_f32_16x16x32_f16(a[kt], b, c, 0, 0, 0);
            }
            int col = ct * 16 + m16;
            float bb = b1[col];
#pragma unroll
            for (int r = 0; r < 4; ++r)
                sT[wid][(quad * 4 + r) * 96 + col] = (_Float16)fmaxf(c[r] + bb, 0.f);
        }
    }
    __syncthreads();
    if (act) {
        half8 a2[3];
#pragma unroll
        for (int kt = 0; kt < 3; ++kt)
            a2[kt] = *(const half8*)(&sT[wid][m16 * 96 + kt * 32 + quad * 8]);
        float dv[4];
#pragma unroll
        for (int r = 0; r < 4; ++r) dv[r] = dis[rbase + quad * 4 + r];
#pragma unroll
        for (int ct = 0; ct < 4; ++ct) {
            f32x4 c = {0.f, 0.f, 0.f, 0.f};
#pragma unroll
            for (int kt = 0; kt < 3; ++kt) {
                half8 b = *(const half8*)(W2t + (size_t)(ct * 16 + m16) * 96 + kt * 32 + quad * 8);
                c = __builtin_amdgcn_mfma_f32_16x16x32_f16(a2[kt], b, c, 0, 0, 0);
            }
#pragma unroll
            for (int r = 0; r < 4; ++r) {
                int orow = rbase + quad * 4 + r;
                // col = ct*16 + m16 -> slice = ct, offset = m16
                __builtin_nontemporal_store((_Float16)(c[r] * dv[r]),
                                            Z2s + ((size_t)ct * N + orow) * 16 + m16);
            }
        }
    }
}

// gemm2: Z3 = dis * (relu(A2 + b2) @ W3), A2 sliced in, Z3 row-major 32 out.
__global__ __launch_bounds__(256) void gemm2_kernel(
        const _Float16* __restrict__ A2, const float* __restrict__ b2,
        const _Float16* __restrict__ W3t, const float* __restrict__ dis,
        _Float16* __restrict__ Z3, int N) {
    int tid = threadIdx.x;
    int wid = tid >> 6;
    int lane = tid & 63;
    int quad = lane >> 4, m16 = lane & 15;
    int tile = blockIdx.x * 4 + wid;
    if (tile >= (N >> 4)) return;  // no barriers in this kernel
    int rbase = tile * 16;
    int row = rbase + m16;
    half8 a[2];
#pragma unroll
    for (int kt = 0; kt < 2; ++kt) {
        int sl = kt * 2 + (quad >> 1);
        half8 v = *(const half8*)(A2 + ((size_t)sl * N + row) * 16 + (quad & 1) * 8);
        int k0 = kt * 32 + quad * 8;
        f32x4 blo = *(const f32x4*)(b2 + k0);
        f32x4 bhi = *(const f32x4*)(b2 + k0 + 4);
        half8 t;
#pragma unroll
        for (int j = 0; j < 4; ++j) t[j] = (_Float16)fmaxf((float)v[j] + blo[j], 0.f);
#pragma unroll
        for (int j = 0; j < 4; ++j) t[4 + j] = (_Float16)fmaxf((float)v[4 + j] + bhi[j], 0.f);
        a[kt] = t;
    }
    float dv[4];
#pragma unroll
    for (int r = 0; r < 4; ++r) dv[r] = dis[rbase + quad * 4 + r];
#pragma unroll
    for (int ct = 0; ct < 2; ++ct) {
        f32x4 c = {0.f, 0.f, 0.f, 0.f};
#pragma unroll
        for (int kt = 0; kt < 2; ++kt) {
            half8 b = *(const half8*)(W3t + (size_t)(ct * 16 + m16) * 64 + kt * 32 + quad * 8);
            c = __builtin_amdgcn_mfma_f32_16x16x32_f16(a[kt], b, c, 0, 0, 0);
        }
        int col = ct * 16 + m16;
#pragma unroll
        for (int r = 0; r < 4; ++r)
            Z3[(size_t)(rbase + quad * 4 + r) * 32 + col] = (_Float16)(c[r] * dv[r]);
    }
}

// Fused agg32 (+b3, relu) -> t3 in LDS -> MFMA @W4t (*dis) -> Z4 fp16.
__global__ __launch_bounds__(512) void agg32_gemm4_kernel(
        const _Float16* __restrict__ hs, const int* __restrict__ rowstart,
        const int* __restrict__ rowdeg, const int* __restrict__ csr,
        const float* __restrict__ dis, const float* __restrict__ b3,
        const _Float16* __restrict__ W4t, _Float16* __restrict__ Z4, int N) {
    __shared__ _Float16 sT[16 * 32];
    int tid = threadIdx.x;
    int wid = tid >> 6;
    int lane = tid & 63;
    int srow = lane >> 5;   // SPAN=32
    int l2 = lane & 31;
    int g = l2 >> 2;        // LPR=4, G=8
    int q = l2 & 3;
    int rbase = blockIdx.x * 16;
    int br = wid * 2 + srow;
    int row = rbase + br;

    if (row < N) {
        int start = rowstart[row];
        int end = start + rowdeg[row];
        float a0[8] = {}, a1[8] = {};
        if (g == 0) {
            half8 v = *(const half8*)(hs + (size_t)row * 32 + 8 * q);
#pragma unroll
            for (int j = 0; j < 8; ++j) a0[j] = (float)v[j];
        }
        int e = start + g;
        for (; e + 8 < end; e += 16) {
            int s0 = __builtin_nontemporal_load(csr + e);
            int s1 = __builtin_nontemporal_load(csr + e + 8);
            half8 v0 = *(const half8*)(hs + (size_t)s0 * 32 + 8 * q);
            half8 v1 = *(const half8*)(hs + (size_t)s1 * 32 + 8 * q);
#pragma unroll
            for (int j = 0; j < 8; ++j) { a0[j] += (float)v0[j]; a1[j] += (float)v1[j]; }
        }
        for (; e < end; e += 8) {
            int s = __builtin_nontemporal_load(csr + e);
            half8 v = *(const half8*)(hs + (size_t)s * 32 + 8 * q);
#pragma unroll
            for (int j = 0; j < 8; ++j) a0[j] += (float)v[j];
        }
#pragma unroll
        for (int j = 0; j < 8; ++j) a0[j] += a1[j];
#pragma unroll
        for (int m = 4; m < 32; m <<= 1) {
#pragma unroll
            for (int j = 0; j < 8; ++j) a0[j] += __shfl_xor(a0[j], m, 64);
        }
        if (g == 0) {
            float d = dis[row];
#pragma unroll
            for (int j = 0; j < 8; ++j) {
                float v = fmaxf(a0[j] * d + b3[8 * q + j], 0.f);
                sT[br * 32 + 8 * q + j] = (_Float16)v;
            }
        }
    }
    __syncthreads();
    if (wid == 0) {
        int quad = lane >> 4, m16 = lane & 15;
        half8 a = *(const half8*)(sT + m16 * 32 + quad * 8);
        half8 b = *(const half8*)(W4t + m16 * 32 + quad * 8);
        f32x4 c = {0.f, 0.f, 0.f, 0.f};
        c = __builtin_amdgcn_mfma_f32_16x16x32_f16(a, b, c, 0, 0, 0);
#pragma unroll
        for (int r = 0; r < 4; ++r) {
            int orow = rbase + quad * 4 + r;
            if (orow < N)
                Z4[(size_t)orow * 16 + m16] = (_Float16)(c[r] * dis[orow]);
        }
    }
}

// Final pull aggregation (F=16, RPW=4): out(fp32) = dis*sum + b4.
__global__ void aggregate_final_kernel(const _Float16* __restrict__ hs,
                                       const int* __restrict__ rowstart,
                                       const int* __restrict__ rowdeg,
                                       const int* __restrict__ csr,
                                       const float* __restrict__ dis,
                                       const float* __restrict__ bias,
                                       float* __restrict__ outp, int N) {
    constexpr int SPAN = 16, LPR = 2, G = 8;
    int wave = (blockIdx.x * blockDim.x + threadIdx.x) >> 6;
    int lane = threadIdx.x & 63;
    int srow = lane / SPAN;
    int l2 = lane % SPAN;
    int g = l2 / LPR;
    int q = l2 % LPR;
    int row = wave * 4 + srow;
    if (row >= N) return;
    int start = rowstart[row];
    int end = start + rowdeg[row];
    float a0[8] = {}, a1[8] = {};
    if (g == 0) {
        half8 v = *(const half8*)(hs + (size_t)row * 16 + 8 * q);
#pragma unroll
        for (int j = 0; j < 8; ++j) a0[j] = (float)v[j];
    }
    int e = start + g;
    for (; e + G < end; e += 2 * G) {
        int s0 = __builtin_nontemporal_load(csr + e);
        int s1 = __builtin_nontemporal_load(csr + e + G);
        half8 v0 = *(const half8*)(hs + (size_t)s0 * 16 + 8 * q);
        half8 v1 = *(const half8*)(hs + (size_t)s1 * 16 + 8 * q);
#pragma unroll
        for (int j = 0; j < 8; ++j) { a0[j] += (float)v0[j]; a1[j] += (float)v1[j]; }
    }
    for (; e < end; e += G) {
        int s = __builtin_nontemporal_load(csr + e);
        half8 v = *(const half8*)(hs + (size_t)s * 16 + 8 * q);
#pragma unroll
        for (int j = 0; j < 8; ++j) a0[j] += (float)v[j];
    }
#pragma unroll
    for (int j = 0; j < 8; ++j) a0[j] += a1[j];
#pragma unroll
    for (int m = LPR; m < SPAN; m <<= 1) {
#pragma unroll
        for (int j = 0; j < 8; ++j) a0[j] += __shfl_xor(a0[j], m, 64);
    }
    if (g == 0) {
        float d = dis[row];
        float4 o0, o1;
        o0.x = a0[0] * d + bias[8 * q + 0];
        o0.y = a0[1] * d + bias[8 * q + 1];
        o0.z = a0[2] * d + bias[8 * q + 2];
        o0.w = a0[3] * d + bias[8 * q + 3];
        o1.x = a0[4] * d + bias[8 * q + 4];
        o1.y = a0[5] * d + bias[8 * q + 5];
        o1.z = a0[6] * d + bias[8 * q + 6];
        o1.w = a0[7] * d + bias[8 * q + 7];
        *(float4*)(outp + (size_t)row * 16 + 8 * q) = o0;
        *(float4*)(outp + (size_t)row * 16 + 8 * q + 4) = o1;
    }
}

static inline int cdiv(long long a, int b) { return (int)((a + b - 1) / b); }

extern "C" void kernel_launch(void* const* d_in, const int* in_sizes, int n_in,
                              void* d_out, int out_size, void* d_ws, size_t ws_size,
                              hipStream_t stream) {
    const float* x  = (const float*)d_in[0];
    const int*   ei = (const int*)d_in[1];
    const float* W1 = (const float*)d_in[2];
    const float* b1 = (const float*)d_in[3];
    const float* W2 = (const float*)d_in[4];
    const float* b2 = (const float*)d_in[5];
    const float* W3 = (const float*)d_in[6];
    const float* b3 = (const float*)d_in[7];
    const float* W4 = (const float*)d_in[8];
    const float* b4 = (const float*)d_in[9];
    float* out = (float*)d_out;

    const int N = in_sizes[0] / 64;   // 100000
    const int E = in_sizes[1] / 2;    // 1600000
    const int* src = ei;
    const int* dst = ei + E;

    int*   bcur     = (int*)d_ws;                 // 788
    int*   rowstart = bcur + 788;                 // 100096
    int*   rowdeg   = rowstart + 100096;          // 100096
    int*   csr      = rowdeg + 100096;            // NBUCK*BCAP (padded slots)
    float* dis      = (float*)(csr + NBUCK * BCAP);  // 100096
    _Float16* hP    = (_Float16*)(dis + 100096);  // N*64 halfs
    _Float16* hQ    = hP + (size_t)N * 64;        // N*64 halfs
    _Float16* wt    = hQ + (size_t)N * 64;        // 14848 halfs (Wt fp16)
    int*   bsort    = (int*)hP;  // NBUCK*BCAP ints, dead before hP's first write

    // --- build: wprep (zeros bcur + converts weights); scatter; bucket sort ---
    wprep_kernel<<<cdiv(14848, TPB), TPB, 0, stream>>>(W1, W2, W3, W4, wt, bcur);
    bscatter_kernel<<<cdiv(E, CHUNK), 512, 0, stream>>>(src, dst, bcur, bsort, E);
    bbuild_kernel<<<NBUCK, 256, 0, stream>>>(bcur, bsort, csr, rowstart, rowdeg, dis,
                                             (const float4*)x, hQ, N);

    const int NCH = cdiv(N, 32);  // 3125 exact

    // --- layer 1: A1 = dis*agg64(hQ) sliced -> hP ---
    agg64s_kernel<<<NCH * 4, 256, 0, stream>>>(hQ, rowstart, rowdeg, csr, dis, hP, N);
    // --- gemm1: hQ = Z2 = dis*(relu(A1@W1+b1)@W2) sliced ---
    gemm1_kernel<<<cdiv(N >> 4, 4), 256, 0, stream>>>(hP, wt + 0, b1, wt + 6144, dis, hQ, N);

    // --- layer 2: A2 = dis*agg64(Z2) sliced -> hP ---
    agg64s_kernel<<<NCH * 4, 256, 0, stream>>>(hQ, rowstart, rowdeg, csr, dis, hP, N);
    // --- gemm2: hQ = Z3 = dis*(relu(A2+b2)@W3) row-major 32 ---
    gemm2_kernel<<<cdiv(N >> 4, 4), 256, 0, stream>>>(hP, b2, wt + 12288, dis, hQ, N);

    // --- agg32+gemm4: hP = Z4 = dis*(relu(agg32(Z3)+b3)@W4) ---
    agg32_gemm4_kernel<<<cdiv(N, 16), 512, 0, stream>>>(
        hQ, rowstart, rowdeg, csr, dis, b3, wt + 14336, hP, N);

    // --- final: out = agg16(hP) + b4 (fp32) ---
    aggregate_final_kernel<<<cdiv(N, 16), TPB, 0, stream>>>(
        hP, rowstart, rowdeg, csr, dis, b4, out, N);
}

// Round 2
// 329.000 us; speedup vs baseline: 1.0371x; 1.0371x over previous
//
#include <hip/hip_runtime.h>

// GCN pull-mode, round 14. r13 post-mortem: slicing made gathers L2-resident
// (FETCH 153->42MB, confirmed) but 4x32B slices DOUBLED request count
// (6.4M vs 3.2M segs/agg) and the L2-hit path serves ~100G req/s -> 64us,
// a wash. Cost model per aggregate: max(misses/40G-lines, requests/100G).
// Round 14: 2 slices x 64B for the F=64 layers — same request count as the
// unsliced r12 (1 seg/edge/slice, 3.2M total) but footprint 6.4MB/XCD-L2
// with parity affinity (slice = bid&1, XCD = bid%8 -> XCDs 0,2,4,6 own
// slice 0) -> ~60% hit vs r12's ~30%. Layers 3/4 keep r12's fused
// structure (footprints 6.4/3.2MB already at/under L2).
//   bbuild: xs 2-sliced -> hQ
//   agg64s2: A1 = dis*agg(hQ) 2-sliced -> hP
//   gemm1:  Z2 = dis*(relu(A1@W1+b1)@W2) 2-sliced -> hQ
//   agg64s2: A2 = dis*agg(hQ) 2-sliced -> hP
//   gemm2:  Z3 = dis*(relu(A2+b2)@W3) row-major 32 -> hQ
//   agg32_gemm4, final: unchanged
// 9 dispatches total.

#define TPB 256
#define NBUCK 782    // ceil(100000/128)
#define BCAP 3072    // fixed slot size; mean 2047, +22 sigma headroom
#define CHUNK 8192   // edges per block in scatter

typedef __attribute__((ext_vector_type(8))) _Float16 half8;
typedef __attribute__((ext_vector_type(4))) _Float16 half4;
typedef __attribute__((ext_vector_type(4))) float f32x4;

// --- Scatter packed edges into fixed bucket slots ---
__global__ void bscatter_kernel(const int* __restrict__ src, const int* __restrict__ dst,
                                int* __restrict__ bcur, int* __restrict__ bsort, int E) {
    __shared__ int h[NBUCK];
    __shared__ int cur[NBUCK];
    int tid = threadIdx.x;
    for (int i = tid; i < NBUCK; i += blockDim.x) h[i] = 0;
    __syncthreads();
    int base = blockIdx.x * CHUNK;
    int lim = min(base + CHUNK, E);
    for (int e = base + tid; e < lim; e += blockDim.x)
        atomicAdd(&h[dst[e] >> 7], 1);
    __syncthreads();
    for (int i = tid; i < NBUCK; i += blockDim.x)
        cur[i] = h[i] ? (atomicAdd(&bcur[i], h[i]) + i * BCAP) : 0;
    __syncthreads();
    for (int e = base + tid; e < lim; e += blockDim.x) {
        int d = dst[e];
        int pos = atomicAdd(&cur[d >> 7], 1);
        bsort[pos] = ((d & 127) << 17) | src[e];  // src < 2^17
    }
}

// --- Per-bucket local sort -> csr slot; rowstart/rowdeg/dis; X prescale ---
// xs written 2-SLICED: hQ[slice][node][32 halfs], slice = feat>>5.
__global__ __launch_bounds__(256) void bbuild_kernel(
        const int* __restrict__ bcur, const int* __restrict__ bsort,
        int* __restrict__ csr, int* __restrict__ rowstart, int* __restrict__ rowdeg,
        float* __restrict__ dis,
        const float4* __restrict__ x4, _Float16* __restrict__ xs,
        int N) {
    __shared__ int ebuf[BCAP];
    __shared__ int obuf[BCAP];
    __shared__ int cnt[128];
    __shared__ int off[129];
    __shared__ float sdis[128];
    int b = blockIdx.x;
    int tid = threadIdx.x;
    int ebase = b * BCAP;
    int n = min(bcur[b], BCAP);
    if (tid < 128) cnt[tid] = 0;
    __syncthreads();
    for (int i = tid; i < n; i += 256) {
        int p = bsort[ebase + i];
        ebuf[i] = p;
        atomicAdd(&cnt[p >> 17], 1);
    }
    __syncthreads();
    if (tid < 64) {
        int lane = tid;
        int v0 = cnt[lane];
#pragma unroll
        for (int d = 1; d < 64; d <<= 1) { int u = __shfl_up(v0, d, 64); if (lane >= d) v0 += u; }
        off[lane + 1] = v0;
        int tot0 = __shfl(v0, 63, 64);
        int v1 = cnt[64 + lane];
#pragma unroll
        for (int d = 1; d < 64; d <<= 1) { int u = __shfl_up(v1, d, 64); if (lane >= d) v1 += u; }
        off[64 + lane + 1] = tot0 + v1;
        if (lane == 0) off[0] = 0;
    }
    __syncthreads();
    int node0 = b << 7;
    if (tid < 128 && node0 + tid < N) {
        int deg = off[tid + 1] - off[tid];
        rowstart[node0 + tid] = ebase + off[tid];
        rowdeg[node0 + tid] = deg;
        float d = rsqrtf((float)deg + 1.0f);
        dis[node0 + tid] = d;
        sdis[tid] = d;
    }
    if (tid < 128) cnt[tid] = off[tid];  // reuse as cursor
    __syncthreads();
    for (int i = tid; i < n; i += 256) {
        int p = ebuf[i];
        int pos = atomicAdd(&cnt[p >> 17], 1);
        obuf[pos] = p & 0x1FFFF;
    }
    __syncthreads();
    for (int i = tid; i < n; i += 256)
        csr[ebase + i] = obuf[i];
    // fused prescale: xs[slice][node][off] = half(x[node][f] * dis[node])
    for (int i = tid; i < 128 * 16; i += 256) {
        int r = i >> 4, c = i & 15;          // c: float4 index, feats 4c..4c+3
        int node = node0 + r;
        if (node >= N) break;
        float d = sdis[r];
        float4 v = x4[(size_t)node * 16 + c];
        half4 h;
        h[0] = (_Float16)(v.x * d); h[1] = (_Float16)(v.y * d);
        h[2] = (_Float16)(v.z * d); h[3] = (_Float16)(v.w * d);
        int sl = c >> 3;                     // slice = (4c)>>5
        int off32 = (c & 7) * 4;             // (4c)&31
        *(half4*)(xs + ((size_t)sl * N + node) * 32 + off32) = h;
    }
}

// Transpose + fp16-convert weights (Wt[m*K+k] = half(W[k*M+m])); zero bcur.
// Sections: W1t 96x64 @0, W2t 64x96 @6144, W3t 32x64 @12288, W4t 16x32 @14336.
__global__ void wprep_kernel(const float* __restrict__ W1, const float* __restrict__ W2,
                             const float* __restrict__ W3, const float* __restrict__ W4,
                             _Float16* __restrict__ wt, int* __restrict__ bcur) {
    int t = blockIdx.x * blockDim.x + threadIdx.x;
    if (t < 788) bcur[t] = 0;
    if (t < 6144) {
        int m = t / 64, k = t % 64;
        wt[t] = (_Float16)W1[k * 96 + m];
    } else if (t < 12288) {
        int i = t - 6144; int m = i / 96, k = i % 96;
        wt[t] = (_Float16)W2[k * 64 + m];
    } else if (t < 14336) {
        int i = t - 12288; int m = i / 64, k = i % 64;
        wt[t] = (_Float16)W3[k * 32 + m];
    } else if (t < 14848) {
        int i = t - 14336; int m = i / 32, k = i % 32;
        wt[t] = (_Float16)W4[k * 16 + m];
    }
}

// 2-sliced F=64 aggregation: block = (slice = bid&1, chunk = bid>>1).
// XCD = bid%8 round-robin -> XCDs {0,2,4,6} own slice 0, {1,3,5,7} slice 1;
// per-XCD gather footprint 6.4MB vs 4MB L2 -> ~60% hit at 1 seg/edge.
// outs[slice][node][32] = dis[node] * (sum_{s in nbr(node)} hs[slice][s][32] + self).
__global__ __launch_bounds__(256) void agg64s2_kernel(
        const _Float16* __restrict__ hs, const int* __restrict__ rowstart,
        const int* __restrict__ rowdeg, const int* __restrict__ csr,
        const float* __restrict__ dis, _Float16* __restrict__ outs, int N) {
    int bid = blockIdx.x;
    int sl = bid & 1;
    int chunk = bid >> 1;
    const _Float16* hb = hs + (size_t)sl * N * 32;
    int tid = threadIdx.x;
    int wid = tid >> 6;
    int lane = tid & 63;
    int srow = lane >> 3;    // 8 rows per wave
    int l2 = lane & 7;
    int g = l2 >> 2;         // 2 edge groups per row
    int q = l2 & 3;          // 4 lanes x half8 = 64-B slice row
    int row = chunk * 32 + wid * 8 + srow;
    if (row >= N) return;    // no barriers below
    int start = rowstart[row];
    int end = start + rowdeg[row];
    float a0[8] = {}, a1[8] = {};
    if (g == 0) {  // self loop
        half8 v = *(const half8*)(hb + (size_t)row * 32 + 8 * q);
#pragma unroll
        for (int j = 0; j < 8; ++j) a0[j] = (float)v[j];
    }
    int e = start + g;
    for (; e + 2 < end; e += 4) {
        int s0 = __builtin_nontemporal_load(csr + e);
        int s1 = __builtin_nontemporal_load(csr + e + 2);
        half8 v0 = *(const half8*)(hb + (size_t)s0 * 32 + 8 * q);
        half8 v1 = *(const half8*)(hb + (size_t)s1 * 32 + 8 * q);
#pragma unroll
        for (int j = 0; j < 8; ++j) { a0[j] += (float)v0[j]; a1[j] += (float)v1[j]; }
    }
    for (; e < end; e += 2) {
        int s = __builtin_nontemporal_load(csr + e);
        half8 v = *(const half8*)(hb + (size_t)s * 32 + 8 * q);
#pragma unroll
        for (int j = 0; j < 8; ++j) a0[j] += (float)v[j];
    }
#pragma unroll
    for (int j = 0; j < 8; ++j) a0[j] += a1[j];
#pragma unroll
    for (int j = 0; j < 8; ++j) a0[j] += __shfl_xor(a0[j], 4, 64);  // combine g
    if (g == 0) {
        float d = dis[row];
        half8 h;
#pragma unroll
        for (int j = 0; j < 8; ++j) h[j] = (_Float16)(a0[j] * d);
        __builtin_nontemporal_store(h, (half8*)(outs + ((size_t)sl * N + row) * 32 + 8 * q));
    }
}

// gemm1: Z2 = dis * (relu(A1@W1 + b1) @ W2), A1 2-sliced in, Z2 2-sliced out.
// 4 waves x 16 rows = 64 rows/block; per-wave sT tile for re-fragmentation.
__global__ __launch_bounds__(256) void gemm1_kernel(
        const _Float16* __restrict__ A1, const _Float16* __restrict__ W1t,
        const float* __restrict__ b1, const _Float16* __restrict__ W2t,
        const float* __restrict__ dis, _Float16* __restrict__ Z2s, int N) {
    __shared__ _Float16 sT[4][16 * 96];
    int tid = threadIdx.x;
    int wid = tid >> 6;
    int lane = tid & 63;
    int quad = lane >> 4, m16 = lane & 15;
    int tile = blockIdx.x * 4 + wid;
    int ntile = N >> 4;  // N divisible by 16
    bool act = tile < ntile;
    int rbase = tile * 16;
    if (act) {
        half8 a[2];
#pragma unroll
        for (int kt = 0; kt < 2; ++kt) {
            // k = kt*32 + quad*8 + j -> slice = kt, in-slice offset = quad*8
            a[kt] = *(const half8*)(A1 + ((size_t)kt * N + rbase + m16) * 32 + quad * 8);
        }
#pragma unroll
        for (int ct = 0; ct < 6; ++ct) {
            f32x4 c = {0.f, 0.f, 0.f, 0.f};
#pragma unroll
            for (int kt = 0; kt < 2; ++kt) {
                half8 b = *(const half8*)(W1t + (size_t)(ct * 16 + m16) * 64 + kt * 32 + quad * 8);
                c = __builtin_amdgcn_mfma_f32_16x16x32_f16(a[kt], b, c, 0, 0, 0);
            }
            int col = ct * 16 + m16;
            float bb = b1[col];
#pragma unroll
            for (int r = 0; r < 4; ++r)
                sT[wid][(quad * 4 + r) * 96 + col] = (_Float16)fmaxf(c[r] + bb, 0.f);
        }
    }
    __syncthreads();
    if (act) {
        half8 a2[3];
#pragma unroll
        for (int kt = 0; kt < 3; ++kt)
            a2[kt] = *(const half8*)(&sT[wid][m16 * 96 + kt * 32 + quad * 8]);
        float dv[4];
#pragma unroll
        for (int r = 0; r < 4; ++r) dv[r] = dis[rbase + quad * 4 + r];
#pragma unroll
        for (int ct = 0; ct < 4; ++ct) {
            f32x4 c = {0.f, 0.f, 0.f, 0.f};
#pragma unroll
            for (int kt = 0; kt < 3; ++kt) {
                half8 b = *(const half8*)(W2t + (size_t)(ct * 16 + m16) * 96 + kt * 32 + quad * 8);
                c = __builtin_amdgcn_mfma_f32_16x16x32_f16(a2[kt], b, c, 0, 0, 0);
            }
            // col = ct*16 + m16 -> slice = ct>>1, offset = (ct&1)*16 + m16
            int sl = ct >> 1;
            int off32 = (ct & 1) * 16 + m16;
#pragma unroll
            for (int r = 0; r < 4; ++r) {
                int orow = rbase + quad * 4 + r;
                __builtin_nontemporal_store((_Float16)(c[r] * dv[r]),
                                            Z2s + ((size_t)sl * N + orow) * 32 + off32);
            }
        }
    }
}

// gemm2: Z3 = dis * (relu(A2 + b2) @ W3), A2 2-sliced in, Z3 row-major 32 out.
__global__ __launch_bounds__(256) void gemm2_kernel(
        const _Float16* __restrict__ A2, const float* __restrict__ b2,
        const _Float16* __restrict__ W3t, const float* __restrict__ dis,
        _Float16* __restrict__ Z3, int N) {
    int tid = threadIdx.x;
    int wid = tid >> 6;
    int lane = tid & 63;
    int quad = lane >> 4, m16 = lane & 15;
    int tile = blockIdx.x * 4 + wid;
    if (tile >= (N >> 4)) return;  // no barriers in this kernel
    int rbase = tile * 16;
    int row = rbase + m16;
    half8 a[2];
#pragma unroll
    for (int kt = 0; kt < 2; ++kt) {
        half8 v = *(const half8*)(A2 + ((size_t)kt * N + row) * 32 + quad * 8);
        int k0 = kt * 32 + quad * 8;
        f32x4 blo = *(const f32x4*)(b2 + k0);
        f32x4 bhi = *(const f32x4*)(b2 + k0 + 4);
        half8 t;
#pragma unroll
        for (int j = 0; j < 4; ++j) t[j] = (_Float16)fmaxf((float)v[j] + blo[j], 0.f);
#pragma unroll
        for (int j = 0; j < 4; ++j) t[4 + j] = (_Float16)fmaxf((float)v[4 + j] + bhi[j], 0.f);
        a[kt] = t;
    }
    float dv[4];
#pragma unroll
    for (int r = 0; r < 4; ++r) dv[r] = dis[rbase + quad * 4 + r];
#pragma unroll
    for (int ct = 0; ct < 2; ++ct) {
        f32x4 c = {0.f, 0.f, 0.f, 0.f};
#pragma unroll
        for (int kt = 0; kt < 2; ++kt) {
            half8 b = *(const half8*)(W3t + (size_t)(ct * 16 + m16) * 64 + kt * 32 + quad * 8);
            c = __builtin_amdgcn_mfma_f32_16x16x32_f16(a[kt], b, c, 0, 0, 0);
        }
        int col = ct * 16 + m16;
#pragma unroll
        for (int r = 0; r < 4; ++r)
            Z3[(size_t)(rbase + quad * 4 + r) * 32 + col] = (_Float16)(c[r] * dv[r]);
    }
}

// Fused agg32 (+b3, relu) -> t3 in LDS -> MFMA @W4t (*dis) -> Z4 fp16.
__global__ __launch_bounds__(512) void agg32_gemm4_kernel(
        const _Float16* __restrict__ hs, const int* __restrict__ rowstart,
        const int* __restrict__ rowdeg, const int* __restrict__ csr,
        const float* __restrict__ dis, const float* __restrict__ b3,
        const _Float16* __restrict__ W4t, _Float16* __restrict__ Z4, int N) {
    __shared__ _Float16 sT[16 * 32];
    int tid = threadIdx.x;
    int wid = tid >> 6;
    int lane = tid & 63;
    int srow = lane >> 5;   // SPAN=32
    int l2 = lane & 31;
    int g = l2 >> 2;        // LPR=4, G=8
    int q = l2 & 3;
    int rbase = blockIdx.x * 16;
    int br = wid * 2 + srow;
    int row = rbase + br;

    if (row < N) {
        int start = rowstart[row];
        int end = start + rowdeg[row];
        float a0[8] = {}, a1[8] = {};
        if (g == 0) {
            half8 v = *(const half8*)(hs + (size_t)row * 32 + 8 * q);
#pragma unroll
            for (int j = 0; j < 8; ++j) a0[j] = (float)v[j];
        }
        int e = start + g;
        for (; e + 8 < end; e += 16) {
            int s0 = __builtin_nontemporal_load(csr + e);
            int s1 = __builtin_nontemporal_load(csr + e + 8);
            half8 v0 = *(const half8*)(hs + (size_t)s0 * 32 + 8 * q);
            half8 v1 = *(const half8*)(hs + (size_t)s1 * 32 + 8 * q);
#pragma unroll
            for (int j = 0; j < 8; ++j) { a0[j] += (float)v0[j]; a1[j] += (float)v1[j]; }
        }
        for (; e < end; e += 8) {
            int s = __builtin_nontemporal_load(csr + e);
            half8 v = *(const half8*)(hs + (size_t)s * 32 + 8 * q);
#pragma unroll
            for (int j = 0; j < 8; ++j) a0[j] += (float)v[j];
        }
#pragma unroll
        for (int j = 0; j < 8; ++j) a0[j] += a1[j];
#pragma unroll
        for (int m = 4; m < 32; m <<= 1) {
#pragma unroll
            for (int j = 0; j < 8; ++j) a0[j] += __shfl_xor(a0[j], m, 64);
        }
        if (g == 0) {
            float d = dis[row];
#pragma unroll
            for (int j = 0; j < 8; ++j) {
                float v = fmaxf(a0[j] * d + b3[8 * q + j], 0.f);
                sT[br * 32 + 8 * q + j] = (_Float16)v;
            }
        }
    }
    __syncthreads();
    if (wid == 0) {
        int quad = lane >> 4, m16 = lane & 15;
        half8 a = *(const half8*)(sT + m16 * 32 + quad * 8);
        half8 b = *(const half8*)(W4t + m16 * 32 + quad * 8);
        f32x4 c = {0.f, 0.f, 0.f, 0.f};
        c = __builtin_amdgcn_mfma_f32_16x16x32_f16(a, b, c, 0, 0, 0);
#pragma unroll
        for (int r = 0; r < 4; ++r) {
            int orow = rbase + quad * 4 + r;
            if (orow < N)
                Z4[(size_t)orow * 16 + m16] = (_Float16)(c[r] * dis[orow]);
        }
    }
}

// Final pull aggregation (F=16, RPW=4): out(fp32) = dis*sum + b4.
__global__ void aggregate_final_kernel(const _Float16* __restrict__ hs,
                                       const int* __restrict__ rowstart,
                                       const int* __restrict__ rowdeg,
                                       const int* __restrict__ csr,
                                       const float* __restrict__ dis,
                                       const float* __restrict__ bias,
                                       float* __restrict__ outp, int N) {
    constexpr int SPAN = 16, LPR = 2, G = 8;
    int wave = (blockIdx.x * blockDim.x + threadIdx.x) >> 6;
    int lane = threadIdx.x & 63;
    int srow = lane / SPAN;
    int l2 = lane % SPAN;
    int g = l2 / LPR;
    int q = l2 % LPR;
    int row = wave * 4 + srow;
    if (row >= N) return;
    int start = rowstart[row];
    int end = start + rowdeg[row];
    float a0[8] = {}, a1[8] = {};
    if (g == 0) {
        half8 v = *(const half8*)(hs + (size_t)row * 16 + 8 * q);
#pragma unroll
        for (int j = 0; j < 8; ++j) a0[j] = (float)v[j];
    }
    int e = start + g;
    for (; e + G < end; e += 2 * G) {
        int s0 = __builtin_nontemporal_load(csr + e);
        int s1 = __builtin_nontemporal_load(csr + e + G);
        half8 v0 = *(const half8*)(hs + (size_t)s0 * 16 + 8 * q);
        half8 v1 = *(const half8*)(hs + (size_t)s1 * 16 + 8 * q);
#pragma unroll
        for (int j = 0; j < 8; ++j) { a0[j] += (float)v0[j]; a1[j] += (float)v1[j]; }
    }
    for (; e < end; e += G) {
        int s = __builtin_nontemporal_load(csr + e);
        half8 v = *(const half8*)(hs + (size_t)s * 16 + 8 * q);
#pragma unroll
        for (int j = 0; j < 8; ++j) a0[j] += (float)v[j];
    }
#pragma unroll
    for (int j = 0; j < 8; ++j) a0[j] += a1[j];
#pragma unroll
    for (int m = LPR; m < SPAN; m <<= 1) {
#pragma unroll
        for (int j = 0; j < 8; ++j) a0[j] += __shfl_xor(a0[j], m, 64);
    }
    if (g == 0) {
        float d = dis[row];
        float4 o0, o1;
        o0.x = a0[0] * d + bias[8 * q + 0];
        o0.y = a0[1] * d + bias[8 * q + 1];
        o0.z = a0[2] * d + bias[8 * q + 2];
        o0.w = a0[3] * d + bias[8 * q + 3];
        o1.x = a0[4] * d + bias[8 * q + 4];
        o1.y = a0[5] * d + bias[8 * q + 5];
        o1.z = a0[6] * d + bias[8 * q + 6];
        o1.w = a0[7] * d + bias[8 * q + 7];
        *(float4*)(outp + (size_t)row * 16 + 8 * q) = o0;
        *(float4*)(outp + (size_t)row * 16 + 8 * q + 4) = o1;
    }
}

static inline int cdiv(long long a, int b) { return (int)((a + b - 1) / b); }

extern "C" void kernel_launch(void* const* d_in, const int* in_sizes, int n_in,
                              void* d_out, int out_size, void* d_ws, size_t ws_size,
                              hipStream_t stream) {
    const float* x  = (const float*)d_in[0];
    const int*   ei = (const int*)d_in[1];
    const float* W1 = (const float*)d_in[2];
    const float* b1 = (const float*)d_in[3];
    const float* W2 = (const float*)d_in[4];
    const float* b2 = (const float*)d_in[5];
    const float* W3 = (const float*)d_in[6];
    const float* b3 = (const float*)d_in[7];
    const float* W4 = (const float*)d_in[8];
    const float* b4 = (const float*)d_in[9];
    float* out = (float*)d_out;

    const int N = in_sizes[0] / 64;   // 100000
    const int E = in_sizes[1] / 2;    // 1600000
    const int* src = ei;
    const int* dst = ei + E;

    int*   bcur     = (int*)d_ws;                 // 788
    int*   rowstart = bcur + 788;                 // 100096
    int*   rowdeg   = rowstart + 100096;          // 100096
    int*   csr      = rowdeg + 100096;            // NBUCK*BCAP (padded slots)
    float* dis      = (float*)(csr + NBUCK * BCAP);  // 100096
    _Float16* hP    = (_Float16*)(dis + 100096);  // N*64 halfs
    _Float16* hQ    = hP + (size_t)N * 64;        // N*64 halfs
    _Float16* wt    = hQ + (size_t)N * 64;        // 14848 halfs (Wt fp16)
    int*   bsort    = (int*)hP;  // NBUCK*BCAP ints, dead before hP's first write

    // --- build: wprep (zeros bcur + converts weights); scatter; bucket sort ---
    wprep_kernel<<<cdiv(14848, TPB), TPB, 0, stream>>>(W1, W2, W3, W4, wt, bcur);
    bscatter_kernel<<<cdiv(E, CHUNK), 512, 0, stream>>>(src, dst, bcur, bsort, E);
    bbuild_kernel<<<NBUCK, 256, 0, stream>>>(bcur, bsort, csr, rowstart, rowdeg, dis,
                                             (const float4*)x, hQ, N);

    const int NCH = cdiv(N, 32);  // 3125 exact

    // --- layer 1: A1 = dis*agg64(hQ) 2-sliced -> hP ---
    agg64s2_kernel<<<NCH * 2, 256, 0, stream>>>(hQ, rowstart, rowdeg, csr, dis, hP, N);
    // --- gemm1: hQ = Z2 = dis*(relu(A1@W1+b1)@W2) 2-sliced ---
    gemm1_kernel<<<cdiv(N >> 4, 4), 256, 0, stream>>>(hP, wt + 0, b1, wt + 6144, dis, hQ, N);

    // --- layer 2: A2 = dis*agg64(Z2) 2-sliced -> hP ---
    agg64s2_kernel<<<NCH * 2, 256, 0, stream>>>(hQ, rowstart, rowdeg, csr, dis, hP, N);
    // --- gemm2: hQ = Z3 = dis*(relu(A2+b2)@W3) row-major 32 ---
    gemm2_kernel<<<cdiv(N >> 4, 4), 256, 0, stream>>>(hP, b2, wt + 12288, dis, hQ, N);

    // --- agg32+gemm4: hP = Z4 = dis*(relu(agg32(Z3)+b3)@W4) ---
    agg32_gemm4_kernel<<<cdiv(N, 16), 512, 0, stream>>>(
        hQ, rowstart, rowdeg, csr, dis, b3, wt + 14336, hP, N);

    // --- final: out = agg16(hP) + b4 (fp32) ---
    aggregate_final_kernel<<<cdiv(N, 16), TPB, 0, stream>>>(
        hP, rowstart, rowdeg, csr, dis, b4, out, N);
}